// Round 1
// baseline (124.684 us; speedup 1.0000x reference)
//
#include <hip/hip_runtime.h>
#include <hip/hip_cooperative_groups.h>

namespace cg = cooperative_groups;

// Fused single-dispatch AUCM loss (cooperative kernel, 2 grid syncs).
//
// Math: with a_i = 1 - p_i over positives, n_j = p_j over negatives,
//   loss = [ Nn*Sum(a^2) + 2*Sum(a)*Sum(n) + P*Sum(n^2)       (squared, O(N))
//            + margin * Sum_{i,j} relu(a_i + n_j) ] / (P*Nn)  (pairwise)
//
// ws layout (every slot written before read — safe under 0xAA poison):
//   [0    .. 2048)  double momPart[64][4]
//   [2048 .. 2304)  int    cnt[64]
//   [2304 .. 4352)  double reluPart[256]
//   [4352 .. 69888) float  posSeg[64][256]

#define NSEG  64
#define MAXP  4096   // max positives per i-slice; 16 KB LDS

__device__ __forceinline__ double wave_reduce_f64(double v) {
    #pragma unroll
    for (int off = 32; off > 0; off >>= 1) v += __shfl_xor(v, off, 64);
    return v;
}

__device__ __forceinline__ float wave_reduce_f32(float v) {
    #pragma unroll
    for (int off = 32; off > 0; off >>= 1) v += __shfl_xor(v, off, 64);
    return v;
}

__global__ __launch_bounds__(256)
void aucm_fused(const float* __restrict__ preds,
                const int* __restrict__ tgt,
                int n,
                double* __restrict__ momPart,   // [NSEG][4]
                int* __restrict__ cnt,          // [NSEG]
                float* __restrict__ posSeg,     // [NSEG][256]
                double* __restrict__ reluPart,  // [NSEG*4]
                float* __restrict__ out,
                float margin)
{
    __shared__ __align__(16) float sA[MAXP];   // phase1: sPos; phase2: slice
    __shared__ int pref[NSEG + 1];
    __shared__ double sRed[4][6];
    __shared__ int sCnt;

    const int tid  = threadIdx.x;
    const int b    = blockIdx.x;     // 0..255
    const int wave = tid >> 6;

    // ---------------- Phase 1: blocks 0..63 scan one 256-elem segment ----
    if (b < NSEG) {
        if (tid == 0) sCnt = 0;
        __syncthreads();

        const int i = b * 256 + tid;
        float a = 0.f, a2 = 0.f, nv = 0.f, n2 = 0.f;
        if (i < n) {
            const float p = preds[i];
            if (tgt[i] == 1) {
                const float av = 1.0f - p;
                a = av; a2 = av * av;
                const int idx = atomicAdd(&sCnt, 1);   // LDS-scope ticket
                sA[idx] = av;
            } else {
                nv = p; n2 = p * p;
            }
        }
        __syncthreads();
        const int c = sCnt;
        if (tid < c) posSeg[b * 256 + tid] = sA[tid];

        const float rA  = wave_reduce_f32(a);
        const float rA2 = wave_reduce_f32(a2);
        const float rN  = wave_reduce_f32(nv);
        const float rN2 = wave_reduce_f32(n2);
        if ((tid & 63) == 0) {
            sRed[wave][0] = (double)rA;  sRed[wave][1] = (double)rA2;
            sRed[wave][2] = (double)rN;  sRed[wave][3] = (double)rN2;
        }
        __syncthreads();
        if (tid == 0) {
            double t0 = 0, t1 = 0, t2 = 0, t3 = 0;
            #pragma unroll
            for (int w = 0; w < 4; ++w) {
                t0 += sRed[w][0]; t1 += sRed[w][1];
                t2 += sRed[w][2]; t3 += sRed[w][3];
            }
            momPart[b * 4 + 0] = t0; momPart[b * 4 + 1] = t1;
            momPart[b * 4 + 2] = t2; momPart[b * 4 + 3] = t3;
            cnt[b] = c;
        }
    }

    cg::this_grid().sync();

    // ---------------- Phase 2: all 256 blocks = 64 j-blocks x 4 i-slices -
    const int jb    = b & 63;
    const int slice = b >> 6;

    // Wave-0 parallel inclusive scan of cnt[] (replaces serial 64-load loop).
    if (tid < 64) {
        int s = cnt[tid];
        #pragma unroll
        for (int d = 1; d < 64; d <<= 1) {
            const int up = __shfl_up(s, d, 64);
            if (tid >= d) s += up;
        }
        pref[tid + 1] = s;
        if (tid == 0) pref[0] = 0;
    }
    __syncthreads();

    const int total = pref[NSEG];
    const int per   = (total + 3) >> 2;
    const int lo    = slice * per;
    const int hi    = min(total, lo + per);
    const int cntS  = max(0, hi - lo);

    // Gather slice [lo, hi) into LDS via binary search over the prefix.
    for (int s = tid; s < cntS; s += 256) {
        const int g = lo + s;
        int l = 0, h = NSEG;
        while (h - l > 1) { const int m = (l + h) >> 1; if (pref[m] <= g) l = m; else h = m; }
        sA[s] = posSeg[l * 256 + (g - pref[l])];
    }
    __syncthreads();

    const int j = jb * 256 + tid;
    float acc = 0.f;
    if (j < n && tgt[j] == 0) {
        const float pj = preds[j];
        int k = 0;
        for (; k + 8 <= cntS; k += 8) {
            const float4 v0 = *reinterpret_cast<const float4*>(&sA[k]);
            const float4 v1 = *reinterpret_cast<const float4*>(&sA[k + 4]);
            // same sequential accumulation order as before (absmax preserved)
            acc += fmaxf(v0.x + pj, 0.f);
            acc += fmaxf(v0.y + pj, 0.f);
            acc += fmaxf(v0.z + pj, 0.f);
            acc += fmaxf(v0.w + pj, 0.f);
            acc += fmaxf(v1.x + pj, 0.f);
            acc += fmaxf(v1.y + pj, 0.f);
            acc += fmaxf(v1.z + pj, 0.f);
            acc += fmaxf(v1.w + pj, 0.f);
        }
        for (; k < cntS; ++k) acc += fmaxf(sA[k] + pj, 0.f);
    }

    double r = wave_reduce_f64((double)acc);
    if ((tid & 63) == 0) sRed[wave][0] = r;
    __syncthreads();
    if (tid == 0)
        reluPart[b] = sRed[0][0] + sRed[1][0] + sRed[2][0] + sRed[3][0];

    cg::this_grid().sync();

    // ---------------- Phase 3: block 0 finalizes -------------------------
    if (b == 0) {
        double mA = 0, mA2 = 0, mN = 0, mN2 = 0, rr = 0, pc = 0;
        for (int i = tid; i < NSEG; i += 256) {
            mA  += momPart[i * 4 + 0]; mA2 += momPart[i * 4 + 1];
            mN  += momPart[i * 4 + 2]; mN2 += momPart[i * 4 + 3];
            pc  += (double)cnt[i];
        }
        for (int i = tid; i < NSEG * 4; i += 256) rr += reluPart[i];

        mA = wave_reduce_f64(mA);  mA2 = wave_reduce_f64(mA2);
        mN = wave_reduce_f64(mN);  mN2 = wave_reduce_f64(mN2);
        rr = wave_reduce_f64(rr);  pc  = wave_reduce_f64(pc);
        if ((tid & 63) == 0) {
            sRed[wave][0] = mA; sRed[wave][1] = mA2; sRed[wave][2] = mN;
            sRed[wave][3] = mN2; sRed[wave][4] = rr; sRed[wave][5] = pc;
        }
        __syncthreads();
        if (tid == 0) {
            double tA = 0, tA2 = 0, tN = 0, tN2 = 0, tR = 0, tP = 0;
            #pragma unroll
            for (int w = 0; w < 4; ++w) {
                tA += sRed[w][0]; tA2 += sRed[w][1]; tN += sRed[w][2];
                tN2 += sRed[w][3]; tR += sRed[w][4]; tP += sRed[w][5];
            }
            const double P  = tP;
            const double Nn = (double)n - tP;
            const double sq = Nn * tA2 + 2.0 * tA * tN + P * tN2;
            out[0] = (float)((sq + (double)margin * tR) / (P * Nn));
        }
    }
}

// ---------------------------------------------------------------------------
extern "C" void kernel_launch(void* const* d_in, const int* in_sizes, int n_in,
                              void* d_out, int out_size, void* d_ws, size_t ws_size,
                              hipStream_t stream) {
    const float* preds = (const float*)d_in[0];
    const int*   tgt   = (const int*)d_in[1];
    float* out = (float*)d_out;
    int n = in_sizes[0];   // 16384 -> exactly NSEG*256

    char* ws = (char*)d_ws;
    double* momPart  = (double*)(ws + 0);
    int*    cnt      = (int*)(ws + 2048);
    double* reluPart = (double*)(ws + 2304);
    float*  posSeg   = (float*)(ws + 4352);
    float margin = 1.0f;

    void* args[] = { (void*)&preds, (void*)&tgt, (void*)&n, (void*)&momPart,
                     (void*)&cnt, (void*)&posSeg, (void*)&reluPart,
                     (void*)&out, (void*)&margin };

    hipLaunchCooperativeKernel((const void*)aucm_fused, dim3(NSEG * 4), dim3(256),
                               args, 0, stream);
}

// Round 2
// 75.099 us; speedup vs baseline: 1.6603x; 1.6603x over previous
//
#include <hip/hip_runtime.h>

// Two-dispatch AUCM loss. No cooperative launch (grid.sync measured ~25us/sync
// on gfx950 — worse than a dispatch boundary). No global atomics, no ws
// zero-init: every ws slot is written before it is read.
//
// Math: with a_i = 1 - p_i over positives, n_j = p_j over negatives,
//   loss = [ Nn*Sum(a^2) + 2*Sum(a)*Sum(n) + P*Sum(n^2)       (squared, O(N))
//            + margin * Sum_{i,j} relu(a_i + n_j) ] / (P*Nn)  (pairwise)
//
// Kernel A: 256 blocks = 64 j-blocks x 4 positive-slices. Each block scans the
// full (L2-resident) input, derives the SAME deterministic positive compaction
// via per-thread-stripe prefix scan (no atomics -> identical partition in every
// block), keeps its slice in LDS, runs the relu pair loop. Block 0 also
// computes the O(N) moment sums in double.
// Kernel B: 1 block finalizes.
//
// ws layout:
//   [0    .. 2048)  double reluPart[256]
//   [2048 .. 2088)  double moms[5]   (sumA, sumA2, sumN, sumN2, posCount)

#define MAXP 4096   // max positives per slice (ceil(N/4) worst case); 16 KB LDS

__device__ __forceinline__ double wave_reduce_f64(double v) {
    #pragma unroll
    for (int off = 32; off > 0; off >>= 1) v += __shfl_xor(v, off, 64);
    return v;
}

// ---------------------------------------------------------------------------
__global__ __launch_bounds__(256)
void aucm_main(const float* __restrict__ preds,
               const int* __restrict__ tgt,
               int n,
               double* __restrict__ reluPart,   // [256]
               double* __restrict__ moms)       // [5]
{
    __shared__ __align__(16) float sA[MAXP];
    __shared__ int sWave[4];
    __shared__ double sRed[4][5];

    const int tid   = threadIdx.x;
    const int lane  = tid & 63;
    const int wave  = tid >> 6;
    const int b     = blockIdx.x;
    const int jb    = b & 63;       // j-block (0..63)
    const int slice = b >> 6;       // positive-slice (0..3)
    const bool doMom = (b == 0);

    // ---- Pass 1: count positives in my 64-elem stripe (elements
    //      tid*4 + u + k*1024, k=0..15, u=0..3 — fixed rule, identical in
    //      every block => deterministic global compaction order).
    unsigned long long mask = 0ull;
    int c = 0;
    double mA = 0, mA2 = 0, mN = 0, mN2 = 0;
    #pragma unroll
    for (int k = 0; k < 16; ++k) {
        const int base = (tid << 2) + (k << 10);
        const int4 t4 = *reinterpret_cast<const int4*>(&tgt[base]);
        const int f0 = (t4.x == 1), f1 = (t4.y == 1),
                  f2 = (t4.z == 1), f3 = (t4.w == 1);
        mask |= ((unsigned long long)f0 << (k * 4 + 0))
              | ((unsigned long long)f1 << (k * 4 + 1))
              | ((unsigned long long)f2 << (k * 4 + 2))
              | ((unsigned long long)f3 << (k * 4 + 3));
        c += f0 + f1 + f2 + f3;
        if (doMom) {   // block-uniform branch
            const float4 p4 = *reinterpret_cast<const float4*>(&preds[base]);
            const float pv[4] = { p4.x, p4.y, p4.z, p4.w };
            const int   fv[4] = { f0, f1, f2, f3 };
            #pragma unroll
            for (int u = 0; u < 4; ++u) {
                if (fv[u]) { const double a = 1.0 - (double)pv[u]; mA += a; mA2 += a * a; }
                else       { const double p = (double)pv[u];       mN += p; mN2 += p * p; }
            }
        }
    }

    // ---- Exclusive prefix over 256 per-thread counts (shfl + LDS).
    int v = c;
    #pragma unroll
    for (int d = 1; d < 64; d <<= 1) {
        const int t = __shfl_up(v, d, 64);
        if (lane >= d) v += t;
    }
    if (lane == 63) sWave[wave] = v;
    __syncthreads();
    int wOff = 0;
    #pragma unroll
    for (int w = 0; w < 4; ++w) if (w < wave) wOff += sWave[w];
    const int total = sWave[0] + sWave[1] + sWave[2] + sWave[3];
    int g = wOff + v - c;                 // my exclusive global compacted index

    const int per  = (total + 3) >> 2;
    const int lo   = slice * per;
    const int hi   = min(total, lo + per);
    const int cntS = max(0, hi - lo);     // <= MAXP always

    // ---- Pass 2: write my stripe's positives that land in [lo, hi).
    if (mask) {
        #pragma unroll
        for (int k = 0; k < 16; ++k) {
            const unsigned gm = (unsigned)((mask >> (k * 4)) & 0xFull);
            if (!gm) continue;
            const int base = (tid << 2) + (k << 10);
            const float4 p4 = *reinterpret_cast<const float4*>(&preds[base]);
            const float pv[4] = { p4.x, p4.y, p4.z, p4.w };
            #pragma unroll
            for (int u = 0; u < 4; ++u) {
                if ((gm >> u) & 1u) {
                    if (g >= lo && g < hi) sA[g - lo] = 1.0f - pv[u];
                    ++g;
                }
            }
        }
    }
    __syncthreads();

    // ---- Relu pair loop: thread owns j = jb*256 + tid.
    const int j = (jb << 8) + tid;
    double accd = 0.0;
    if (j < n && tgt[j] == 0) {
        const float pj = preds[j];
        int k = 0;
        while (k < cntS) {
            const int end = min(cntS, k + 64);
            float accf = 0.f;
            for (; k + 8 <= end; k += 8) {
                const float4 v0 = *reinterpret_cast<const float4*>(&sA[k]);
                const float4 v1 = *reinterpret_cast<const float4*>(&sA[k + 4]);
                accf += fmaxf(v0.x + pj, 0.f);
                accf += fmaxf(v0.y + pj, 0.f);
                accf += fmaxf(v0.z + pj, 0.f);
                accf += fmaxf(v0.w + pj, 0.f);
                accf += fmaxf(v1.x + pj, 0.f);
                accf += fmaxf(v1.y + pj, 0.f);
                accf += fmaxf(v1.z + pj, 0.f);
                accf += fmaxf(v1.w + pj, 0.f);
            }
            for (; k < end; ++k) accf += fmaxf(sA[k] + pj, 0.f);
            accd += (double)accf;         // chunked double flush
        }
    }

    double r = wave_reduce_f64(accd);
    if (lane == 0) sRed[wave][0] = r;
    if (doMom) {
        const double rA  = wave_reduce_f64(mA);
        const double rA2 = wave_reduce_f64(mA2);
        const double rN  = wave_reduce_f64(mN);
        const double rN2 = wave_reduce_f64(mN2);
        if (lane == 0) {
            sRed[wave][1] = rA; sRed[wave][2] = rA2;
            sRed[wave][3] = rN; sRed[wave][4] = rN2;
        }
    }
    __syncthreads();
    if (tid == 0) {
        reluPart[b] = sRed[0][0] + sRed[1][0] + sRed[2][0] + sRed[3][0];
        if (doMom) {
            double tA = 0, tA2 = 0, tN = 0, tN2 = 0;
            #pragma unroll
            for (int w = 0; w < 4; ++w) {
                tA += sRed[w][1]; tA2 += sRed[w][2];
                tN += sRed[w][3]; tN2 += sRed[w][4];
            }
            moms[0] = tA; moms[1] = tA2; moms[2] = tN; moms[3] = tN2;
            moms[4] = (double)total;
        }
    }
}

// ---------------------------------------------------------------------------
__global__ __launch_bounds__(256)
void aucm_fin(const double* __restrict__ reluPart,
              const double* __restrict__ moms,
              int n, float* __restrict__ out, float margin)
{
    __shared__ double sRed[4];
    const int tid  = threadIdx.x;
    const int lane = tid & 63;
    const int wave = tid >> 6;

    double r = reluPart[tid];             // exactly 256 partials
    r = wave_reduce_f64(r);
    if (lane == 0) sRed[wave] = r;
    __syncthreads();
    if (tid == 0) {
        const double tR = sRed[0] + sRed[1] + sRed[2] + sRed[3];
        const double tA  = moms[0], tA2 = moms[1];
        const double tN  = moms[2], tN2 = moms[3];
        const double P   = moms[4];
        const double Nn  = (double)n - P;
        const double sq  = Nn * tA2 + 2.0 * tA * tN + P * tN2;
        out[0] = (float)((sq + (double)margin * tR) / (P * Nn));
    }
}

// ---------------------------------------------------------------------------
extern "C" void kernel_launch(void* const* d_in, const int* in_sizes, int n_in,
                              void* d_out, int out_size, void* d_ws, size_t ws_size,
                              hipStream_t stream) {
    const float* preds = (const float*)d_in[0];
    const int*   tgt   = (const int*)d_in[1];
    float* out = (float*)d_out;
    const int n = in_sizes[0];   // 16384

    char* ws = (char*)d_ws;
    double* reluPart = (double*)(ws + 0);
    double* moms     = (double*)(ws + 2048);

    aucm_main<<<256, 256, 0, stream>>>(preds, tgt, n, reluPart, moms);
    aucm_fin<<<1, 256, 0, stream>>>(reluPart, moms, n, out, 1.0f /*MARGIN*/);
}

// Round 3
// 72.138 us; speedup vs baseline: 1.7284x; 1.0410x over previous
//
#include <hip/hip_runtime.h>

// Two-dispatch AUCM loss — round-0 dataflow (known good) minus the finalize
// dispatch, which is folded into kernel 2 via a last-block-arrival finalize.
//
// Math: with a_i = 1 - p_i over positives, n_j = p_j over negatives,
//   loss = [ Nn*Sum(a^2) + 2*Sum(a)*Sum(n) + P*Sum(n^2)       (squared, O(N))
//            + margin * Sum_{i,j} relu(a_i + n_j) ] / (P*Nn)  (pairwise)
//
// No ws zero-init needed: every ws slot (incl. the arrival counter, which
// kernel 1 resets each launch) is written before it is read — 0xAA-poison safe.
//
// ws layout:
//   [0    .. 2048)  double momPart[64][4]   (sumA, sumA2, sumN, sumN2 per block)
//   [2048 .. 2304)  int    cnt[64]          (positives per 256-elem segment)
//   [2304 .. 4352)  double reluPart[256]
//   [4352 .. 4356)  int    arrival counter  (reset to 0 by kernel 1)
//   [4608 .. 70144) float  posSeg[64][256]  (per-segment compacted a_i)

#define NSEG  64
#define MAXP  4096   // max positives per i-slice (N/4 worst case); 16 KB LDS

__device__ __forceinline__ double wave_reduce_f64(double v) {
    #pragma unroll
    for (int off = 32; off > 0; off >>= 1) v += __shfl_xor(v, off, 64);
    return v;
}

__device__ __forceinline__ float wave_reduce_f32(float v) {
    #pragma unroll
    for (int off = 32; off > 0; off >>= 1) v += __shfl_xor(v, off, 64);
    return v;
}

// ---------------------------------------------------------------------------
// Kernel 1: 64 blocks x 256 threads, exactly one element per thread.
// Per-block LDS compaction of positives -> global segment; moment partials.
// Block 0 additionally resets the arrival counter for kernel 2.
__global__ __launch_bounds__(256)
void aucm_scan(const float* __restrict__ preds,
               const int* __restrict__ tgt,
               int n,
               double* __restrict__ momPart,  // [NSEG][4]
               int* __restrict__ cnt,         // [NSEG]
               float* __restrict__ posSeg,    // [NSEG][256]
               int* __restrict__ counter) {
    __shared__ float sPos[256];
    __shared__ int sCnt;
    __shared__ double sRed[4][4];

    const int tid = threadIdx.x;
    const int b   = blockIdx.x;
    const int wave = tid >> 6;
    if (tid == 0) sCnt = 0;
    __syncthreads();

    const int i = b * 256 + tid;
    float a = 0.f, a2 = 0.f, nv = 0.f, n2 = 0.f;
    if (i < n) {
        const float p = preds[i];
        if (tgt[i] == 1) {
            const float av = 1.0f - p;
            a = av; a2 = av * av;
            const int idx = atomicAdd(&sCnt, 1);   // LDS-scope ticket
            sPos[idx] = av;
        } else {
            nv = p; n2 = p * p;
        }
    }
    __syncthreads();
    const int c = sCnt;
    if (tid < c) posSeg[b * 256 + tid] = sPos[tid];

    const float rA  = wave_reduce_f32(a);
    const float rA2 = wave_reduce_f32(a2);
    const float rN  = wave_reduce_f32(nv);
    const float rN2 = wave_reduce_f32(n2);
    if ((tid & 63) == 0) {
        sRed[wave][0] = (double)rA;  sRed[wave][1] = (double)rA2;
        sRed[wave][2] = (double)rN;  sRed[wave][3] = (double)rN2;
    }
    __syncthreads();
    if (tid == 0) {
        double t0 = 0, t1 = 0, t2 = 0, t3 = 0;
        #pragma unroll
        for (int w = 0; w < 4; ++w) {
            t0 += sRed[w][0]; t1 += sRed[w][1];
            t2 += sRed[w][2]; t3 += sRed[w][3];
        }
        momPart[b * 4 + 0] = t0; momPart[b * 4 + 1] = t1;
        momPart[b * 4 + 2] = t2; momPart[b * 4 + 3] = t3;
        cnt[b] = c;
        if (b == 0)   // reset arrival counter (agent scope: write-through)
            __hip_atomic_store(counter, 0, __ATOMIC_RELEASE,
                               __HIP_MEMORY_SCOPE_AGENT);
    }
}

// ---------------------------------------------------------------------------
// Kernel 2: 256 blocks = 64 j-blocks x 4 i-slices, 256 threads.
// Gather this block's positive slice into LDS, run the relu pair loop, then
// the LAST arriving block finalizes (replacing the old 3rd dispatch).
__global__ __launch_bounds__(256)
void aucm_relu(const float* __restrict__ preds,
               const int* __restrict__ tgt,
               int n,
               const int* __restrict__ cnt,
               const float* __restrict__ posSeg,
               const double* __restrict__ momPart,
               double* __restrict__ reluPart,
               int* __restrict__ counter,
               float* __restrict__ out, float margin) {
    __shared__ int pref[NSEG + 1];
    __shared__ __align__(16) float sA[MAXP];
    __shared__ double sRed[4][6];
    __shared__ int sLast;

    const int tid   = threadIdx.x;
    const int lane  = tid & 63;
    const int wave  = tid >> 6;
    const int b     = blockIdx.x;
    const int jb    = b & 63;   // j-block index (0..63)
    const int slice = b >> 6;   // i-slice (0..3)

    // Wave-parallel inclusive scan of cnt[] (replaces serial 64-load loop —
    // the old thread-0 loop was 64 dependent L2 hits replicated in 256 blocks).
    if (tid < 64) {
        int s = cnt[tid];
        #pragma unroll
        for (int d = 1; d < 64; d <<= 1) {
            const int t = __shfl_up(s, d, 64);
            if (lane >= d) s += t;
        }
        pref[tid + 1] = s;
        if (tid == 0) pref[0] = 0;
    }
    __syncthreads();

    const int total = pref[NSEG];
    const int per   = (total + 3) >> 2;
    const int lo    = slice * per;
    const int hi    = min(total, lo + per);
    const int cntS  = max(0, hi - lo);   // <= MAXP always

    // Gather slice [lo, hi) into LDS via binary search over the prefix.
    for (int s = tid; s < cntS; s += 256) {
        const int g = lo + s;
        int l = 0, h = NSEG;
        while (h - l > 1) { const int m = (l + h) >> 1; if (pref[m] <= g) l = m; else h = m; }
        sA[s] = posSeg[l * 256 + (g - pref[l])];
    }
    __syncthreads();

    // Relu pair loop: thread owns j = jb*256 + tid. LDS reads are wave-uniform
    // (bank broadcast, conflict-free). Dual accumulators halve the dep chain.
    const int j = (jb << 8) + tid;
    double accd = 0.0;
    if (j < n && tgt[j] == 0) {
        const float pj = preds[j];
        int k = 0;
        while (k < cntS) {
            const int end = min(cntS, k + 64);
            float a0 = 0.f, a1 = 0.f;
            for (; k + 8 <= end; k += 8) {
                const float4 v0 = *reinterpret_cast<const float4*>(&sA[k]);
                const float4 v1 = *reinterpret_cast<const float4*>(&sA[k + 4]);
                a0 += fmaxf(v0.x + pj, 0.f);
                a1 += fmaxf(v0.y + pj, 0.f);
                a0 += fmaxf(v0.z + pj, 0.f);
                a1 += fmaxf(v0.w + pj, 0.f);
                a0 += fmaxf(v1.x + pj, 0.f);
                a1 += fmaxf(v1.y + pj, 0.f);
                a0 += fmaxf(v1.z + pj, 0.f);
                a1 += fmaxf(v1.w + pj, 0.f);
            }
            float at = a0 + a1;
            for (; k < end; ++k) at += fmaxf(sA[k] + pj, 0.f);
            accd += (double)at;          // chunked double flush
        }
    }

    double r = wave_reduce_f64(accd);
    if (lane == 0) sRed[wave][0] = r;
    __syncthreads();
    if (tid == 0) {
        const double part = sRed[0][0] + sRed[1][0] + sRed[2][0] + sRed[3][0];
        // Release-publish my partial, then arrive. ACQ_REL on the RMW makes all
        // prior blocks' release-stores visible to the last arriver.
        __hip_atomic_store(&reluPart[b], part, __ATOMIC_RELEASE,
                           __HIP_MEMORY_SCOPE_AGENT);
        const int old = __hip_atomic_fetch_add(counter, 1, __ATOMIC_ACQ_REL,
                                               __HIP_MEMORY_SCOPE_AGENT);
        sLast = (old == NSEG * 4 - 1);
    }
    __syncthreads();

    if (sLast) {
        // ---- Finalize (identical summation order to the old 3rd kernel). ----
        double mA = 0, mA2 = 0, mN = 0, mN2 = 0, rr = 0;
        for (int i = tid; i < NSEG; i += 256) {
            mA  += momPart[i * 4 + 0]; mA2 += momPart[i * 4 + 1];
            mN  += momPart[i * 4 + 2]; mN2 += momPart[i * 4 + 3];
        }
        for (int i = tid; i < NSEG * 4; i += 256)
            rr += __hip_atomic_load(&reluPart[i], __ATOMIC_RELAXED,
                                    __HIP_MEMORY_SCOPE_AGENT);

        mA = wave_reduce_f64(mA);  mA2 = wave_reduce_f64(mA2);
        mN = wave_reduce_f64(mN);  mN2 = wave_reduce_f64(mN2);
        rr = wave_reduce_f64(rr);
        if (lane == 0) {
            sRed[wave][1] = mA; sRed[wave][2] = mA2;
            sRed[wave][3] = mN; sRed[wave][4] = mN2; sRed[wave][5] = rr;
        }
        __syncthreads();
        if (tid == 0) {
            double tA = 0, tA2 = 0, tN = 0, tN2 = 0, tR = 0;
            #pragma unroll
            for (int w = 0; w < 4; ++w) {
                tA += sRed[w][1]; tA2 += sRed[w][2]; tN += sRed[w][3];
                tN2 += sRed[w][4]; tR += sRed[w][5];
            }
            const double P  = (double)total;   // == sum(cnt), same value as before
            const double Nn = (double)n - P;
            const double sq = Nn * tA2 + 2.0 * tA * tN + P * tN2;
            out[0] = (float)((sq + (double)margin * tR) / (P * Nn));
        }
    }
}

// ---------------------------------------------------------------------------
extern "C" void kernel_launch(void* const* d_in, const int* in_sizes, int n_in,
                              void* d_out, int out_size, void* d_ws, size_t ws_size,
                              hipStream_t stream) {
    const float* preds = (const float*)d_in[0];
    const int*   tgt   = (const int*)d_in[1];
    float* out = (float*)d_out;
    const int n = in_sizes[0];   // 16384 -> exactly NSEG*256

    char* ws = (char*)d_ws;
    double* momPart  = (double*)(ws + 0);
    int*    cnt      = (int*)(ws + 2048);
    double* reluPart = (double*)(ws + 2304);
    int*    counter  = (int*)(ws + 4352);
    float*  posSeg   = (float*)(ws + 4608);

    aucm_scan<<<NSEG, 256, 0, stream>>>(preds, tgt, n, momPart, cnt, posSeg,
                                        counter);
    aucm_relu<<<NSEG * 4, 256, 0, stream>>>(preds, tgt, n, cnt, posSeg,
                                            momPart, reluPart, counter, out,
                                            1.0f /*MARGIN*/);
}

// Round 4
// 68.694 us; speedup vs baseline: 1.8151x; 1.0501x over previous
//
#include <hip/hip_runtime.h>

// Two-dispatch AUCM loss — round-0 dataflow minus the finalize dispatch,
// folded into kernel 2 via last-block-arrival finalize.
//
// Atomic-ordering fix vs previous round: arrival uses a RELEASE fetch_add
// (writeback only); the ONE last-arriving block issues the single agent-scope
// ACQUIRE fence. The previous ACQ_REL-per-block caused ~256 XCD-L2
// invalidations that evicted sibling blocks' cached preds/tgt/posSeg mid-loop.
//
// Math: with a_i = 1 - p_i over positives, n_j = p_j over negatives,
//   loss = [ Nn*Sum(a^2) + 2*Sum(a)*Sum(n) + P*Sum(n^2)       (squared, O(N))
//            + margin * Sum_{i,j} relu(a_i + n_j) ] / (P*Nn)  (pairwise)
//
// No ws zero-init needed: every ws slot (incl. the arrival counter, reset by
// kernel 1) is written before it is read — 0xAA-poison safe.
//
// ws layout:
//   [0    .. 2048)  double momPart[64][4]
//   [2048 .. 2304)  int    cnt[64]
//   [2304 .. 4352)  double reluPart[256]
//   [4352 .. 4356)  int    arrival counter  (reset to 0 by kernel 1)
//   [4608 .. 70144) float  posSeg[64][256]

#define NSEG  64
#define MAXP  4096   // max positives per i-slice (N/4 worst case); 16 KB LDS

__device__ __forceinline__ double wave_reduce_f64(double v) {
    #pragma unroll
    for (int off = 32; off > 0; off >>= 1) v += __shfl_xor(v, off, 64);
    return v;
}

__device__ __forceinline__ float wave_reduce_f32(float v) {
    #pragma unroll
    for (int off = 32; off > 0; off >>= 1) v += __shfl_xor(v, off, 64);
    return v;
}

// ---------------------------------------------------------------------------
// Kernel 1: 64 blocks x 256 threads, one element per thread.
// Per-block LDS compaction of positives -> global segment; moment partials.
// Block 0 also resets the arrival counter for kernel 2.
__global__ __launch_bounds__(256)
void aucm_scan(const float* __restrict__ preds,
               const int* __restrict__ tgt,
               int n,
               double* __restrict__ momPart,  // [NSEG][4]
               int* __restrict__ cnt,         // [NSEG]
               float* __restrict__ posSeg,    // [NSEG][256]
               int* __restrict__ counter) {
    __shared__ float sPos[256];
    __shared__ int sCnt;
    __shared__ double sRed[4][4];

    const int tid = threadIdx.x;
    const int b   = blockIdx.x;
    const int wave = tid >> 6;
    if (tid == 0) sCnt = 0;
    __syncthreads();

    const int i = b * 256 + tid;
    float a = 0.f, a2 = 0.f, nv = 0.f, n2 = 0.f;
    if (i < n) {
        const float p = preds[i];
        if (tgt[i] == 1) {
            const float av = 1.0f - p;
            a = av; a2 = av * av;
            const int idx = atomicAdd(&sCnt, 1);   // LDS-scope ticket
            sPos[idx] = av;
        } else {
            nv = p; n2 = p * p;
        }
    }
    __syncthreads();
    const int c = sCnt;
    if (tid < c) posSeg[b * 256 + tid] = sPos[tid];

    const float rA  = wave_reduce_f32(a);
    const float rA2 = wave_reduce_f32(a2);
    const float rN  = wave_reduce_f32(nv);
    const float rN2 = wave_reduce_f32(n2);
    if ((tid & 63) == 0) {
        sRed[wave][0] = (double)rA;  sRed[wave][1] = (double)rA2;
        sRed[wave][2] = (double)rN;  sRed[wave][3] = (double)rN2;
    }
    __syncthreads();
    if (tid == 0) {
        double t0 = 0, t1 = 0, t2 = 0, t3 = 0;
        #pragma unroll
        for (int w = 0; w < 4; ++w) {
            t0 += sRed[w][0]; t1 += sRed[w][1];
            t2 += sRed[w][2]; t3 += sRed[w][3];
        }
        momPart[b * 4 + 0] = t0; momPart[b * 4 + 1] = t1;
        momPart[b * 4 + 2] = t2; momPart[b * 4 + 3] = t3;
        cnt[b] = c;
        if (b == 0)
            __hip_atomic_store(counter, 0, __ATOMIC_RELAXED,
                               __HIP_MEMORY_SCOPE_AGENT);
    }
}

// ---------------------------------------------------------------------------
// Kernel 2: 256 blocks = 64 j-blocks x 4 i-slices, 256 threads.
// Gather this block's positive slice into LDS, run the relu pair loop; the
// LAST arriving block finalizes (single acquire fence, then reads partials).
__global__ __launch_bounds__(256)
void aucm_relu(const float* __restrict__ preds,
               const int* __restrict__ tgt,
               int n,
               const int* __restrict__ cnt,
               const float* __restrict__ posSeg,
               const double* __restrict__ momPart,
               double* __restrict__ reluPart,
               int* __restrict__ counter,
               float* __restrict__ out, float margin) {
    __shared__ int pref[NSEG + 1];
    __shared__ __align__(16) float sA[MAXP];
    __shared__ double sRed[4][6];
    __shared__ int sLast;

    const int tid   = threadIdx.x;
    const int lane  = tid & 63;
    const int wave  = tid >> 6;
    const int b     = blockIdx.x;
    const int jb    = b & 63;   // j-block index (0..63)
    const int slice = b >> 6;   // i-slice (0..3)

    // Wave-parallel inclusive scan of cnt[] (wave 0).
    if (tid < 64) {
        int s = cnt[tid];
        #pragma unroll
        for (int d = 1; d < 64; d <<= 1) {
            const int t = __shfl_up(s, d, 64);
            if (lane >= d) s += t;
        }
        pref[tid + 1] = s;
        if (tid == 0) pref[0] = 0;
    }
    __syncthreads();

    const int total = pref[NSEG];
    const int per   = (total + 3) >> 2;
    const int lo    = slice * per;
    const int hi    = min(total, lo + per);
    const int cntS  = max(0, hi - lo);   // <= MAXP always

    // Gather slice [lo, hi) into LDS via binary search over the prefix.
    for (int s = tid; s < cntS; s += 256) {
        const int g = lo + s;
        int l = 0, h = NSEG;
        while (h - l > 1) { const int m = (l + h) >> 1; if (pref[m] <= g) l = m; else h = m; }
        sA[s] = posSeg[l * 256 + (g - pref[l])];
    }
    __syncthreads();

    // Relu pair loop: thread owns j = jb*256 + tid. LDS reads are wave-uniform
    // broadcasts (conflict-free). Dual accumulators halve the dep chain.
    const int j = (jb << 8) + tid;
    double accd = 0.0;
    if (j < n && tgt[j] == 0) {
        const float pj = preds[j];
        int k = 0;
        while (k < cntS) {
            const int end = min(cntS, k + 64);
            float a0 = 0.f, a1 = 0.f;
            for (; k + 8 <= end; k += 8) {
                const float4 v0 = *reinterpret_cast<const float4*>(&sA[k]);
                const float4 v1 = *reinterpret_cast<const float4*>(&sA[k + 4]);
                a0 += fmaxf(v0.x + pj, 0.f);
                a1 += fmaxf(v0.y + pj, 0.f);
                a0 += fmaxf(v0.z + pj, 0.f);
                a1 += fmaxf(v0.w + pj, 0.f);
                a0 += fmaxf(v1.x + pj, 0.f);
                a1 += fmaxf(v1.y + pj, 0.f);
                a0 += fmaxf(v1.z + pj, 0.f);
                a1 += fmaxf(v1.w + pj, 0.f);
            }
            float at = a0 + a1;
            for (; k < end; ++k) at += fmaxf(sA[k] + pj, 0.f);
            accd += (double)at;          // chunked double flush
        }
    }

    double r = wave_reduce_f64(accd);
    if (lane == 0) sRed[wave][0] = r;
    __syncthreads();
    if (tid == 0) {
        const double part = sRed[0][0] + sRed[1][0] + sRed[2][0] + sRed[3][0];
        // Relaxed publish; the RELEASE RMW orders it (writeback only — no L2
        // invalidate, unlike ACQ_REL which thrashed sibling blocks' L2).
        __hip_atomic_store(&reluPart[b], part, __ATOMIC_RELAXED,
                           __HIP_MEMORY_SCOPE_AGENT);
        const int old = __hip_atomic_fetch_add(counter, 1, __ATOMIC_RELEASE,
                                               __HIP_MEMORY_SCOPE_AGENT);
        sLast = (old == NSEG * 4 - 1);
    }
    __syncthreads();

    if (sLast) {
        // The ONE acquire in the whole kernel: synchronizes-with all release
        // RMWs, invalidates this block's stale L1/L2 before reading partials.
        if (tid == 0)
            __builtin_amdgcn_fence(__ATOMIC_ACQUIRE, "agent");
        __syncthreads();

        double mA = 0, mA2 = 0, mN = 0, mN2 = 0, rr = 0;
        for (int i = tid; i < NSEG; i += 256) {
            mA  += momPart[i * 4 + 0]; mA2 += momPart[i * 4 + 1];
            mN  += momPart[i * 4 + 2]; mN2 += momPart[i * 4 + 3];
        }
        for (int i = tid; i < NSEG * 4; i += 256)
            rr += __hip_atomic_load(&reluPart[i], __ATOMIC_RELAXED,
                                    __HIP_MEMORY_SCOPE_AGENT);

        mA = wave_reduce_f64(mA);  mA2 = wave_reduce_f64(mA2);
        mN = wave_reduce_f64(mN);  mN2 = wave_reduce_f64(mN2);
        rr = wave_reduce_f64(rr);
        if (lane == 0) {
            sRed[wave][1] = mA; sRed[wave][2] = mA2;
            sRed[wave][3] = mN; sRed[wave][4] = mN2; sRed[wave][5] = rr;
        }
        __syncthreads();
        if (tid == 0) {
            double tA = 0, tA2 = 0, tN = 0, tN2 = 0, tR = 0;
            #pragma unroll
            for (int w = 0; w < 4; ++w) {
                tA += sRed[w][1]; tA2 += sRed[w][2]; tN += sRed[w][3];
                tN2 += sRed[w][4]; tR += sRed[w][5];
            }
            const double P  = (double)total;   // == sum(cnt)
            const double Nn = (double)n - P;
            const double sq = Nn * tA2 + 2.0 * tA * tN + P * tN2;
            out[0] = (float)((sq + (double)margin * tR) / (P * Nn));
        }
    }
}

// ---------------------------------------------------------------------------
extern "C" void kernel_launch(void* const* d_in, const int* in_sizes, int n_in,
                              void* d_out, int out_size, void* d_ws, size_t ws_size,
                              hipStream_t stream) {
    const float* preds = (const float*)d_in[0];
    const int*   tgt   = (const int*)d_in[1];
    float* out = (float*)d_out;
    const int n = in_sizes[0];   // 16384 -> exactly NSEG*256

    char* ws = (char*)d_ws;
    double* momPart  = (double*)(ws + 0);
    int*    cnt      = (int*)(ws + 2048);
    double* reluPart = (double*)(ws + 2304);
    int*    counter  = (int*)(ws + 4352);
    float*  posSeg   = (float*)(ws + 4608);

    aucm_scan<<<NSEG, 256, 0, stream>>>(preds, tgt, n, momPart, cnt, posSeg,
                                        counter);
    aucm_relu<<<NSEG * 4, 256, 0, stream>>>(preds, tgt, n, cnt, posSeg,
                                            momPart, reluPart, counter, out,
                                            1.0f /*MARGIN*/);
}

// Round 5
// 62.926 us; speedup vs baseline: 1.9815x; 1.0917x over previous
//
#include <hip/hip_runtime.h>

// Two-dispatch AUCM loss, pair-tiled for occupancy.
//
// Grid of kernel A = 64 j-blocks x 16 i-tiles = 1024 blocks (4 blocks/CU,
// 16 waves/CU — vs 1 wave/SIMD in the old 2-phase structure). Each block:
//   - loads its 1024-element i-tile (int4/float4, 4 elems/thread),
//   - compacts the tile's positives (a_i = 1-p_i) into LDS via a
//     deterministic shfl prefix scan (no global compaction, no phase-1
//     kernel, no cnt[]/posSeg dependency),
//   - each thread owns j = jb*256+tid and accumulates relu(a_i + p_j) over
//     the tile's positives (wave-uniform LDS broadcasts, conflict-free).
// The 16 jb==0 blocks additionally compute per-tile moment sums in double.
// Kernel B: 1 block sums 1024 relu partials + 16x5 moments, writes out.
//
// Math: with a_i = 1 - p_i over positives, n_j = p_j over negatives,
//   loss = [ Nn*Sum(a^2) + 2*Sum(a)*Sum(n) + P*Sum(n^2)       (squared, O(N))
//            + margin * Sum_{i,j} relu(a_i + n_j) ] / (P*Nn)  (pairwise)
//
// No ws zero-init: every ws slot read by kernel B is written by kernel A.
// ws layout:
//   [0    .. 8192)  double reluPart[1024]
//   [8192 .. 9216)  double momPart[16][8]  (sumA, sumA2, sumN, sumN2, cnt)

#define TILE  1024
#define NTIL  16     // 16 * 1024 = 16384
#define NJB   64     // 64 * 256  = 16384

__device__ __forceinline__ double wave_reduce_f64(double v) {
    #pragma unroll
    for (int off = 32; off > 0; off >>= 1) v += __shfl_xor(v, off, 64);
    return v;
}

// ---------------------------------------------------------------------------
__global__ __launch_bounds__(256)
void aucm_pair(const float* __restrict__ preds,
               const int* __restrict__ tgt,
               int n,
               double* __restrict__ reluPart,   // [1024]
               double* __restrict__ momPart)    // [16][8]
{
    __shared__ __align__(16) float sP[TILE];
    __shared__ int sWaveC[4];
    __shared__ double sRed[4][6];

    const int tid  = threadIdx.x;
    const int lane = tid & 63;
    const int wave = tid >> 6;
    const int b    = blockIdx.x;
    const int jb   = b & (NJB - 1);   // j-block (0..63)
    const int it   = b >> 6;          // i-tile  (0..15)
    const bool doMom = (jb == 0);

    // ---- Load my 4 contiguous i-tile elements (vectorized, coalesced).
    const int base = it * TILE + (tid << 2);
    const int4   t4 = *reinterpret_cast<const int4*>(&tgt[base]);
    const float4 p4 = *reinterpret_cast<const float4*>(&preds[base]);
    const int f0 = (t4.x == 1), f1 = (t4.y == 1),
              f2 = (t4.z == 1), f3 = (t4.w == 1);
    const int c = f0 + f1 + f2 + f3;

    // ---- Deterministic compaction offset: shfl inclusive scan + wave offs.
    int v = c;
    #pragma unroll
    for (int d = 1; d < 64; d <<= 1) {
        const int t = __shfl_up(v, d, 64);
        if (lane >= d) v += t;
    }
    if (lane == 63) sWaveC[wave] = v;
    __syncthreads();
    int wOff = 0;
    #pragma unroll
    for (int w = 0; w < 4; ++w) if (w < wave) wOff += sWaveC[w];
    const int cntP = sWaveC[0] + sWaveC[1] + sWaveC[2] + sWaveC[3];

    int g = wOff + v - c;              // exclusive start, element order kept
    if (f0) sP[g++] = 1.0f - p4.x;
    if (f1) sP[g++] = 1.0f - p4.y;
    if (f2) sP[g++] = 1.0f - p4.z;
    if (f3) sP[g++] = 1.0f - p4.w;

    // ---- Per-tile moments (only the 16 jb==0 blocks), all in double.
    double mA = 0, mA2 = 0, mN = 0, mN2 = 0;
    if (doMom) {
        const float pv[4] = { p4.x, p4.y, p4.z, p4.w };
        const int   fv[4] = { f0, f1, f2, f3 };
        #pragma unroll
        for (int u = 0; u < 4; ++u) {
            if (fv[u]) { const double a = 1.0 - (double)pv[u]; mA += a; mA2 += a * a; }
            else       { const double p = (double)pv[u];       mN += p; mN2 += p * p; }
        }
    }
    __syncthreads();

    // ---- Relu pair loop: thread owns j = jb*256 + tid (j < n always).
    const int j = (jb << 8) + tid;
    double accd = 0.0;
    if (tgt[j] == 0) {
        const float pj = preds[j];
        int k = 0;
        while (k < cntP) {
            const int end = min(cntP, k + 64);
            float a0 = 0.f, a1 = 0.f;
            for (; k + 8 <= end; k += 8) {
                const float4 v0 = *reinterpret_cast<const float4*>(&sP[k]);
                const float4 v1 = *reinterpret_cast<const float4*>(&sP[k + 4]);
                a0 += fmaxf(v0.x + pj, 0.f);
                a1 += fmaxf(v0.y + pj, 0.f);
                a0 += fmaxf(v0.z + pj, 0.f);
                a1 += fmaxf(v0.w + pj, 0.f);
                a0 += fmaxf(v1.x + pj, 0.f);
                a1 += fmaxf(v1.y + pj, 0.f);
                a0 += fmaxf(v1.z + pj, 0.f);
                a1 += fmaxf(v1.w + pj, 0.f);
            }
            float at = a0 + a1;
            for (; k < end; ++k) at += fmaxf(sP[k] + pj, 0.f);
            accd += (double)at;        // chunked double flush (<=64 f32 adds)
        }
    }

    double r = wave_reduce_f64(accd);
    if (lane == 0) sRed[wave][0] = r;
    if (doMom) {
        const double rA  = wave_reduce_f64(mA);
        const double rA2 = wave_reduce_f64(mA2);
        const double rN  = wave_reduce_f64(mN);
        const double rN2 = wave_reduce_f64(mN2);
        if (lane == 0) {
            sRed[wave][1] = rA; sRed[wave][2] = rA2;
            sRed[wave][3] = rN; sRed[wave][4] = rN2;
        }
    }
    __syncthreads();
    if (tid == 0) {
        reluPart[b] = sRed[0][0] + sRed[1][0] + sRed[2][0] + sRed[3][0];
        if (doMom) {
            double tA = 0, tA2 = 0, tN = 0, tN2 = 0;
            #pragma unroll
            for (int w = 0; w < 4; ++w) {
                tA += sRed[w][1]; tA2 += sRed[w][2];
                tN += sRed[w][3]; tN2 += sRed[w][4];
            }
            momPart[it * 8 + 0] = tA;  momPart[it * 8 + 1] = tA2;
            momPart[it * 8 + 2] = tN;  momPart[it * 8 + 3] = tN2;
            momPart[it * 8 + 4] = (double)cntP;
        }
    }
}

// ---------------------------------------------------------------------------
__global__ __launch_bounds__(256)
void aucm_fin(const double* __restrict__ reluPart,
              const double* __restrict__ momPart,
              int n, float* __restrict__ out, float margin)
{
    __shared__ double sRedR[4];
    const int tid  = threadIdx.x;
    const int lane = tid & 63;
    const int wave = tid >> 6;

    // Relu partials: 1024 doubles, 4 per thread (deterministic order).
    double r = reluPart[tid] + reluPart[tid + 256]
             + reluPart[tid + 512] + reluPart[tid + 768];
    r = wave_reduce_f64(r);
    if (lane == 0) sRedR[wave] = r;

    // Moments: 16 tiles x 5 values, handled by wave 0 lanes 0..15.
    double mA = 0, mA2 = 0, mN = 0, mN2 = 0, pc = 0;
    if (tid < NTIL) {
        mA  = momPart[tid * 8 + 0]; mA2 = momPart[tid * 8 + 1];
        mN  = momPart[tid * 8 + 2]; mN2 = momPart[tid * 8 + 3];
        pc  = momPart[tid * 8 + 4];
    }
    if (wave == 0) {
        mA  = wave_reduce_f64(mA);  mA2 = wave_reduce_f64(mA2);
        mN  = wave_reduce_f64(mN);  mN2 = wave_reduce_f64(mN2);
        pc  = wave_reduce_f64(pc);
    }
    __syncthreads();
    if (tid == 0) {
        const double tR = sRedR[0] + sRedR[1] + sRedR[2] + sRedR[3];
        const double P  = pc;
        const double Nn = (double)n - P;
        const double sq = Nn * mA2 + 2.0 * mA * mN + P * mN2;
        out[0] = (float)((sq + (double)margin * tR) / (P * Nn));
    }
}

// ---------------------------------------------------------------------------
extern "C" void kernel_launch(void* const* d_in, const int* in_sizes, int n_in,
                              void* d_out, int out_size, void* d_ws, size_t ws_size,
                              hipStream_t stream) {
    const float* preds = (const float*)d_in[0];
    const int*   tgt   = (const int*)d_in[1];
    float* out = (float*)d_out;
    const int n = in_sizes[0];   // 16384 = NTIL*TILE = NJB*256

    char* ws = (char*)d_ws;
    double* reluPart = (double*)(ws + 0);
    double* momPart  = (double*)(ws + 8192);

    aucm_pair<<<NJB * NTIL, 256, 0, stream>>>(preds, tgt, n, reluPart, momPart);
    aucm_fin<<<1, 256, 0, stream>>>(reluPart, momPart, n, out, 1.0f /*MARGIN*/);
}